// Round 6
// baseline (1477.316 us; speedup 1.0000x reference)
//
#include <hip/hip_runtime.h>
#include <hip/hip_fp16.h>

// GraphEncoder: 3x ChebConv(K=6) + GroupNorm(8)/ReLU + dense readout.
// R6: UNWEIGHTED edge list (colIdx only, 4 B/edge). L_hat = -Dm A Dm factors into
//     row/col scalings: Horner state kept dis-scaled (GEMM epilogue scales slices
//     j>=1 by dis_i), passes do plain neighbor sums + row-constant multiply.
//     R5's k_scatter was line-granule write-bound (161 MB for 20.5 MB array).
// R5: 2-stage split-K readout. R4: fp16 intermediates, fp32 accum.

#define NN 160000
#define EE 2560000
#define FD2 256

typedef __attribute__((ext_vector_type(8))) _Float16 half8;
typedef __attribute__((ext_vector_type(4))) float floatx4;

__device__ inline float2 h2f2(unsigned u) {
  __half2 h = __builtin_bit_cast(__half2, u);
  return __half22float2(h);
}
__device__ inline unsigned short f2h(float f) {
  return __builtin_bit_cast(unsigned short, __float2half_rn(f));
}
__device__ inline unsigned packh2(float a, float b) {
  return __builtin_bit_cast(unsigned, __floats2half2_rn(a, b));
}

// ----------------- CSR build -----------------
__global__ __launch_bounds__(256) void k_zero(int* __restrict__ p, int n) {
  int i = blockIdx.x * 256 + threadIdx.x;
  if (i < n) p[i] = 0;
}

__global__ __launch_bounds__(256) void k_hist(const int* __restrict__ ei, int* __restrict__ deg) {
  int e = blockIdx.x * 256 + threadIdx.x;
  if (e < EE) atomicAdd(&deg[ei[e]], 1);
}

__global__ __launch_bounds__(256) void k_dis(const int* __restrict__ deg, float* __restrict__ dis) {
  int i = blockIdx.x * 256 + threadIdx.x;
  if (i < NN) { int d = deg[i]; dis[i] = d > 0 ? rsqrtf((float)d) : 0.f; }
}

__global__ __launch_bounds__(256) void k_scan1(const int* __restrict__ deg, int* __restrict__ rowStart,
                                               int* __restrict__ bsum) {
  __shared__ int s[256];
  int tid = threadIdx.x;
  int i = blockIdx.x * 256 + tid;        // 625*256 = NN exact
  int v = deg[i];
  s[tid] = v;
  __syncthreads();
  for (int off = 1; off < 256; off <<= 1) {
    int t = (tid >= off) ? s[tid - off] : 0;
    __syncthreads();
    s[tid] += t;
    __syncthreads();
  }
  rowStart[i] = s[tid] - v;
  if (tid == 255) bsum[blockIdx.x] = s[255];
}

__global__ void k_scan2(int* __restrict__ bsum, int nb) {
  __shared__ int s[1024];
  int tid = threadIdx.x;
  int v = (tid < nb) ? bsum[tid] : 0;
  s[tid] = v;
  __syncthreads();
  for (int off = 1; off < 1024; off <<= 1) {
    int t = (tid >= off) ? s[tid - off] : 0;
    __syncthreads();
    s[tid] += t;
    __syncthreads();
  }
  if (tid < nb) bsum[tid] = s[tid] - v;
}

__global__ __launch_bounds__(256) void k_scan3(int* __restrict__ rowStart, const int* __restrict__ bsum,
                                               int* __restrict__ cur) {
  int i = blockIdx.x * 256 + threadIdx.x;
  int v = rowStart[i] + bsum[blockIdx.x];
  rowStart[i] = v;
  cur[i] = v;                            // scatter cursor starts at rowStart
  if (i == 0) rowStart[NN] = EE;
}

__global__ __launch_bounds__(256) void k_scatter(const int* __restrict__ ei, int* __restrict__ cur,
                                                 int* __restrict__ colIdx) {
  int e = blockIdx.x * 256 + threadIdx.x;
  if (e >= EE) return;
  int r = ei[e];
  int pos = atomicAdd(&cur[r], 1);
  colIdx[pos] = ei[EE + e];
}

// ----------------- Layer 0 (cin=3) classic Chebyshev, dual T/S (S = dis*T) ----------
__global__ __launch_bounds__(256) void k_copyx(const float* __restrict__ x, const float* __restrict__ dis,
                                               float4* __restrict__ T, float4* __restrict__ S,
                                               unsigned short* __restrict__ TxAll) {
  int i = blockIdx.x * 256 + threadIdx.x;
  if (i >= NN) return;
  float x0 = x[3 * i], x1 = x[3 * i + 1], x2 = x[3 * i + 2];
  float di = dis[i];
  T[i] = make_float4(x0, x1, x2, 0.f);
  S[i] = make_float4(di * x0, di * x1, di * x2, 0.f);
  unsigned short* tp = TxAll + i * 32;
  tp[0] = f2h(x0); tp[1] = f2h(x1); tp[2] = f2h(x2);
}

template <int MODE>   // 1: Tnew = prop; 2: Tnew = 2*prop - Tdst (in place)
__global__ __launch_bounds__(256) void k_prop3(const float4* __restrict__ Ssrc, float4* __restrict__ Tdst,
                                               float4* __restrict__ Sdst, unsigned short* __restrict__ TxAll,
                                               int ks, const int* __restrict__ rowStart,
                                               const int* __restrict__ colIdx, const float* __restrict__ dis) {
  int i = blockIdx.x * 256 + threadIdx.x;
  if (i >= NN) return;
  float s0 = 0.f, s1 = 0.f, s2 = 0.f;
  int e = rowStart[i], e1 = rowStart[i + 1];
  for (; e + 3 < e1; e += 4) {
    int c0 = colIdx[e], c1 = colIdx[e + 1], c2 = colIdx[e + 2], c3 = colIdx[e + 3];
    float4 f0 = Ssrc[c0], f1 = Ssrc[c1], f2 = Ssrc[c2], f3 = Ssrc[c3];
    s0 += f0.x + f1.x + f2.x + f3.x;
    s1 += f0.y + f1.y + f2.y + f3.y;
    s2 += f0.z + f1.z + f2.z + f3.z;
  }
  for (; e < e1; e++) {
    float4 f0 = Ssrc[colIdx[e]];
    s0 += f0.x; s1 += f0.y; s2 += f0.z;
  }
  float di = dis[i];
  float a0 = -di * s0, a1 = -di * s1, a2 = -di * s2;   // prop(T)[i] = -dis_i * sum S[col]
  if (MODE == 2) {
    float4 tp = Tdst[i];
    a0 = 2.f * a0 - tp.x;
    a1 = 2.f * a1 - tp.y;
    a2 = 2.f * a2 - tp.z;
  }
  Tdst[i] = make_float4(a0, a1, a2, 0.f);
  Sdst[i] = make_float4(di * a0, di * a1, di * a2, 0.f);
  unsigned short* tp = TxAll + i * 32 + ks * 3;
  tp[0] = f2h(a0); tp[1] = f2h(a1); tp[2] = f2h(a2);
}

// W0 (18 x 128) -> transposed padded fp16 (128 x 32)
__global__ __launch_bounds__(256) void k_padW0(const float* __restrict__ W0, unsigned short* __restrict__ Bt) {
  int idx = blockIdx.x * 256 + threadIdx.x;   // 128*32
  if (idx >= 128 * 32) return;
  int co = idx >> 5, t = idx & 31;
  Bt[co * 32 + t] = (t < 18) ? f2h(W0[t * 128 + co]) : (unsigned short)0;
}

// C_j = sum_k a[k][j] W_k, written TRANSPOSED fp16: Bt[(j*COUT+co)*CIN + ci]
template <int CIN, int COUT>
__global__ __launch_bounds__(256) void k_combine(const float* __restrict__ W, unsigned short* __restrict__ Bt) {
  int idx = blockIdx.x * 256 + threadIdx.x;
  if (idx >= CIN * 6 * COUT) return;
  int co = idx % COUT;
  int j  = (idx / COUT) % 6;
  int ci = idx / (6 * COUT);
  float c0, c1, c2, c3, c4, c5;
  switch (j) {
    case 0:  c0 = 1;  c1 = 0;  c2 = -1; c3 = 0;   c4 = 1;  c5 = 0;   break;
    case 1:  c0 = 0;  c1 = 1;  c2 = 0;  c3 = -3;  c4 = 0;  c5 = 5;   break;
    case 2:  c0 = 0;  c1 = 0;  c2 = 2;  c3 = 0;   c4 = -8; c5 = 0;   break;
    case 3:  c0 = 0;  c1 = 0;  c2 = 0;  c3 = 4;   c4 = 0;  c5 = -20; break;
    case 4:  c0 = 0;  c1 = 0;  c2 = 0;  c3 = 0;   c4 = 8;  c5 = 0;   break;
    default: c0 = 0;  c1 = 0;  c2 = 0;  c3 = 0;   c4 = 0;  c5 = 16;  break;
  }
  float s = 0.f;
  s += c0 * W[(0 * CIN + ci) * COUT + co];
  s += c1 * W[(1 * CIN + ci) * COUT + co];
  s += c2 * W[(2 * CIN + ci) * COUT + co];
  s += c3 * W[(3 * CIN + ci) * COUT + co];
  s += c4 * W[(4 * CIN + ci) * COUT + co];
  s += c5 * W[(5 * CIN + ci) * COUT + co];
  Bt[(j * COUT + co) * CIN + ci] = f2h(s);
}

// ----------------- MFMA f16 GEMM -> Y fp16; slices >= scaleFrom scaled by dis_i --------
template <int KDIM, int COUT>
__global__ __launch_bounds__(256) void k_gemm(const unsigned short* __restrict__ A,
                                              const unsigned short* __restrict__ Bt,
                                              const float* __restrict__ dis, int scaleFrom,
                                              unsigned short* __restrict__ Y) {
  constexpr int KP = KDIM + 8;
  __shared__ unsigned short As[64 * KP];
  __shared__ unsigned short Bs[64 * KP];
  int i0 = blockIdx.x * 64;
  int c0 = blockIdx.y * 64;
  for (int idx = threadIdx.x; idx < 64 * (KDIM / 8); idx += 256) {
    int row = idx / (KDIM / 8), seg = idx % (KDIM / 8);
    uint4 v = ((const uint4*)A)[(size_t)(i0 + row) * (KDIM / 8) + seg];
    *reinterpret_cast<uint4*>(&As[row * KP + seg * 8]) = v;
  }
  for (int idx = threadIdx.x; idx < 64 * (KDIM / 8); idx += 256) {
    int row = idx / (KDIM / 8), seg = idx % (KDIM / 8);
    uint4 v = ((const uint4*)Bt)[(size_t)(c0 + row) * (KDIM / 8) + seg];
    *reinterpret_cast<uint4*>(&Bs[row * KP + seg * 8]) = v;
  }
  __syncthreads();
  int w = threadIdx.x >> 6, lane = threadIdx.x & 63;
  int mn = lane & 15, q = lane >> 4;
  floatx4 acc[4];
#pragma unroll
  for (int cb = 0; cb < 4; cb++) acc[cb] = {0.f, 0.f, 0.f, 0.f};
#pragma unroll
  for (int ks = 0; ks < KDIM / 32; ks++) {
    half8 af = *reinterpret_cast<const half8*>(&As[(16 * w + mn) * KP + ks * 32 + q * 8]);
#pragma unroll
    for (int cb = 0; cb < 4; cb++) {
      half8 bf = *reinterpret_cast<const half8*>(&Bs[(cb * 16 + mn) * KP + ks * 32 + q * 8]);
      acc[cb] = __builtin_amdgcn_mfma_f32_16x16x32_f16(af, bf, acc[cb], 0, 0, 0);
    }
  }
  float dv[4];
#pragma unroll
  for (int r = 0; r < 4; r++) dv[r] = dis[i0 + 16 * w + q * 4 + r];
  // C/D layout: col = lane&15, row = (lane>>4)*4 + reg  [m89; dtype-independent]
#pragma unroll
  for (int cb = 0; cb < 4; cb++) {
    int jc = c0 + cb * 16 + mn;
    int slice = jc / COUT, cc = jc % COUT;
    unsigned short* dst = Y + (size_t)slice * NN * COUT + cc;
#pragma unroll
    for (int r = 0; r < 4; r++) {
      int i = i0 + 16 * w + q * 4 + r;
      float sc = (slice >= scaleFrom) ? dv[r] : 1.f;
      dst[(size_t)i * COUT] = f2h(acc[cb][r] * sc);
    }
  }
}

// ----------------- Horner prop step (fp16, unweighted gather) -----------------------
// Ydst in: Ytilde_j (scaled) or Y0 (final); out: g_j = Ytilde - dis^2*sum, or F = Y0 - dis*sum.
template <int CPN>
__global__ __launch_bounds__(256) void k_horner(const unsigned* __restrict__ Ysrc, unsigned* __restrict__ Ydst,
                                                const int* __restrict__ rowStart, const int* __restrict__ colIdx,
                                                const float* __restrict__ dis, int isFinal) {
  int t = blockIdx.x * 256 + threadIdx.x;
  int i = t / CPN;
  int cp = t % CPN;
  float acc0 = 0.f, acc1 = 0.f;
  int e = rowStart[i], e1 = rowStart[i + 1];
  for (; e + 7 < e1; e += 8) {
    int cA[8];
#pragma unroll
    for (int k = 0; k < 8; k++) cA[k] = colIdx[e + k];
    unsigned u[8];
#pragma unroll
    for (int k = 0; k < 8; k++) u[k] = Ysrc[(size_t)cA[k] * CPN + cp];
#pragma unroll
    for (int k = 0; k < 8; k++) {
      float2 f = h2f2(u[k]);
      acc0 += f.x;
      acc1 += f.y;
    }
  }
  for (; e < e1; e++) {
    float2 f = h2f2(Ysrc[(size_t)colIdx[e] * CPN + cp]);
    acc0 += f.x;
    acc1 += f.y;
  }
  float di = dis[i];
  float coef = isFinal ? di : di * di;
  float2 y = h2f2(Ydst[(size_t)i * CPN + cp]);
  Ydst[(size_t)i * CPN + cp] = packh2(y.x - coef * acc0, y.y - coef * acc1);
}

// ----------------- GroupNorm(8) + bias + ReLU (fp16 in/out) -----------------
template <int CPG>
__global__ __launch_bounds__(256) void k_gn(const unsigned short* __restrict__ src, const float* __restrict__ bias,
                                            const float* __restrict__ gamma, const float* __restrict__ beta,
                                            unsigned short* __restrict__ dst) {
  constexpr int C = CPG * 8;
  int t = blockIdx.x * 256 + threadIdx.x;   // (node, group); grid 5000*256 = NN*8 exact
  int i = t >> 3, g = t & 7;
  float v[CPG];
  const unsigned* p = reinterpret_cast<const unsigned*>(src + (size_t)i * C + g * CPG);
#pragma unroll
  for (int q = 0; q < CPG / 2; q++) {
    float2 f = h2f2(p[q]);
    v[2 * q] = f.x; v[2 * q + 1] = f.y;
  }
  float mean = 0.f;
#pragma unroll
  for (int c = 0; c < CPG; c++) { v[c] += bias[g * CPG + c]; mean += v[c]; }
  mean *= (1.f / CPG);
  float var = 0.f;
#pragma unroll
  for (int c = 0; c < CPG; c++) { float d = v[c] - mean; var += d * d; }
  var *= (1.f / CPG);
  float rs = rsqrtf(var + 1e-5f);
  unsigned* dp = reinterpret_cast<unsigned*>(dst + (size_t)i * C + g * CPG);
#pragma unroll
  for (int q = 0; q < CPG / 2; q++) {
    float o0 = fmaxf((v[2 * q] - mean) * rs * gamma[g * CPG + 2 * q] + beta[g * CPG + 2 * q], 0.f);
    float o1 = fmaxf((v[2 * q + 1] - mean) * rs * gamma[g * CPG + 2 * q + 1] + beta[g * CPG + 2 * q + 1], 0.f);
    dp[q] = packh2(o0, o1);
  }
}

// ----------------- Readout: (16 x 320000) @ (320000 x 128), 2-stage split-K ----------
__global__ __launch_bounds__(256) void k_final1(const unsigned short* __restrict__ h3,
                                                const float* __restrict__ Wl,
                                                float* __restrict__ part) {
  __shared__ float hs[16 * FD2];
  __shared__ float red[2048];
  int d0 = blockIdx.x * FD2;
  const unsigned* h3u = reinterpret_cast<const unsigned*>(h3);
  for (int idx = threadIdx.x; idx < 16 * (FD2 / 2); idx += 256) {
    int b = idx / (FD2 / 2), dq = idx % (FD2 / 2);
    float2 f = h2f2(h3u[(size_t)b * 160000 + (d0 >> 1) + dq]);
    hs[b * FD2 + 2 * dq] = f.x;
    hs[b * FD2 + 2 * dq + 1] = f.y;
  }
  __syncthreads();
  int w = threadIdx.x >> 6, lane = threadIdx.x & 63;
  float a0[16], a1[16];
#pragma unroll
  for (int b = 0; b < 16; b++) { a0[b] = 0.f; a1[b] = 0.f; }
  const float* wp = Wl + (size_t)(d0 + w * (FD2 / 4)) * 128 + 2 * lane;
#pragma unroll 2
  for (int r = 0; r < FD2 / 4; r++) {
    float2 wv = *reinterpret_cast<const float2*>(wp + (size_t)r * 128);
    int row = w * (FD2 / 4) + r;
#pragma unroll
    for (int b = 0; b < 16; b++) {
      float h = hs[b * FD2 + row];
      a0[b] += wv.x * h;
      a1[b] += wv.y * h;
    }
  }
  float2* red2 = reinterpret_cast<float2*>(red);
  for (int ww = 0; ww < 4; ww++) {
    if (w == ww) {
#pragma unroll
      for (int b = 0; b < 16; b++) {
        if (ww == 0) {
          red2[b * 64 + lane] = make_float2(a0[b], a1[b]);
        } else {
          float2 r2 = red2[b * 64 + lane];
          r2.x += a0[b]; r2.y += a1[b];
          red2[b * 64 + lane] = r2;
        }
      }
    }
    __syncthreads();
  }
  for (int i = threadIdx.x; i < 2048; i += 256)
    part[(size_t)blockIdx.x * 2048 + i] = red[i];
}

__global__ __launch_bounds__(256) void k_final2(const float* __restrict__ part, const float* __restrict__ bl,
                                                float* __restrict__ out) {
  int o = blockIdx.x * 256 + threadIdx.x;   // 0..2047
  float s = bl[o & 127];
#pragma unroll 10
  for (int p = 0; p < 1250; p++) s += part[(size_t)p * 2048 + o];
  out[o] = s;
}

// ----------------- launcher -----------------
extern "C" void kernel_launch(void* const* d_in, const int* in_sizes, int n_in,
                              void* d_out, int out_size, void* d_ws, size_t ws_size,
                              hipStream_t stream) {
  const float* x   = (const float*)d_in[0];
  const int*   ei  = (const int*)d_in[1];   // harness stages ALL integer inputs as int32
  const float* W0  = (const float*)d_in[2];
  const float* b0  = (const float*)d_in[3];
  const float* g0  = (const float*)d_in[4];
  const float* be0 = (const float*)d_in[5];
  const float* W1  = (const float*)d_in[6];
  const float* b1  = (const float*)d_in[7];
  const float* g1  = (const float*)d_in[8];
  const float* be1 = (const float*)d_in[9];
  const float* W2  = (const float*)d_in[10];
  const float* b2  = (const float*)d_in[11];
  const float* g2  = (const float*)d_in[12];
  const float* be2 = (const float*)d_in[13];
  const float* Wl  = (const float*)d_in[14];
  const float* bl  = (const float*)d_in[15];
  float* out = (float*)d_out;
  (void)in_sizes; (void)n_in; (void)out_size; (void)ws_size;

  char* pw = (char*)d_ws;
  auto carve = [&](size_t bytes) -> void* {
    void* r = (void*)pw;
    pw += (bytes + 255) & ~(size_t)255;
    return r;
  };
  int*            deg      = (int*)   carve((size_t)NN * 4);
  int*            cur      = (int*)   carve((size_t)NN * 4);
  int*            rowStart = (int*)   carve((size_t)(NN + 1) * 4);
  int*            bsum     = (int*)   carve(1024 * 4);
  float*          dis      = (float*) carve((size_t)NN * 4);
  int*            colIdx   = (int*)   carve((size_t)EE * 4);
  unsigned short* Cwt      = (unsigned short*)carve((size_t)384 * 128 * 2);
  unsigned short* TxAll    = (unsigned short*)carve((size_t)NN * 32 * 2);
  float4*         T_A      = (float4*)carve((size_t)NN * 16);
  float4*         T_B      = (float4*)carve((size_t)NN * 16);
  float4*         S_A      = (float4*)carve((size_t)NN * 16);
  float4*         S_B      = (float4*)carve((size_t)NN * 16);
  unsigned short* Hbuf     = (unsigned short*)carve((size_t)NN * 128 * 2);
  unsigned short* Ybuf     = (unsigned short*)carve((size_t)NN * 384 * 2);
  float*          part     = (float*) carve((size_t)1250 * 2048 * 4);

  // ---- CSR build (unweighted: colIdx only) ----
  k_zero<<<625, 256, 0, stream>>>(deg, NN);
  k_hist<<<10000, 256, 0, stream>>>(ei, deg);
  k_dis<<<625, 256, 0, stream>>>(deg, dis);
  k_scan1<<<625, 256, 0, stream>>>(deg, rowStart, bsum);
  k_scan2<<<1, 1024, 0, stream>>>(bsum, 625);
  k_scan3<<<625, 256, 0, stream>>>(rowStart, bsum, cur);
  k_scatter<<<10000, 256, 0, stream>>>(ei, cur, colIdx);

  // ---- Layer 0 (3 -> 128): classic Chebyshev, dual T/S, TxAll (NN x 32 fp16) ----
  k_zero<<<10000, 256, 0, stream>>>((int*)TxAll, NN * 16);
  k_copyx<<<625, 256, 0, stream>>>(x, dis, T_A, S_A, TxAll);
  k_prop3<1><<<625, 256, 0, stream>>>(S_A, T_B, S_B, TxAll, 1, rowStart, colIdx, dis);
  k_prop3<2><<<625, 256, 0, stream>>>(S_B, T_A, S_A, TxAll, 2, rowStart, colIdx, dis);
  k_prop3<2><<<625, 256, 0, stream>>>(S_A, T_B, S_B, TxAll, 3, rowStart, colIdx, dis);
  k_prop3<2><<<625, 256, 0, stream>>>(S_B, T_A, S_A, TxAll, 4, rowStart, colIdx, dis);
  k_prop3<2><<<625, 256, 0, stream>>>(S_A, T_B, S_B, TxAll, 5, rowStart, colIdx, dis);
  k_padW0<<<16, 256, 0, stream>>>(W0, Cwt);
  k_gemm<32, 128><<<dim3(2500, 2), 256, 0, stream>>>(TxAll, Cwt, dis, 99, Ybuf);
  k_gn<16><<<5000, 256, 0, stream>>>(Ybuf, b0, g0, be0, Hbuf);

  // ---- Layer 1 (128 -> 64): MFMA GEMM (slices 1..5 dis-scaled) + 5 Horner passes ----
  k_combine<128, 64><<<192, 256, 0, stream>>>(W1, Cwt);
  k_gemm<128, 64><<<dim3(2500, 6), 256, 0, stream>>>(Hbuf, Cwt, dis, 1, Ybuf);
  for (int j = 4; j >= 0; j--)
    k_horner<32><<<20000, 256, 0, stream>>>((unsigned*)(Ybuf + (size_t)(j + 1) * NN * 64),
                                            (unsigned*)(Ybuf + (size_t)j * NN * 64),
                                            rowStart, colIdx, dis, j == 0);
  k_gn<8><<<5000, 256, 0, stream>>>(Ybuf, b1, g1, be1, Hbuf);

  // ---- Layer 2 (64 -> 32) ----
  k_combine<64, 32><<<48, 256, 0, stream>>>(W2, Cwt);
  k_gemm<64, 32><<<dim3(2500, 3), 256, 0, stream>>>(Hbuf, Cwt, dis, 1, Ybuf);
  for (int j = 4; j >= 0; j--)
    k_horner<16><<<10000, 256, 0, stream>>>((unsigned*)(Ybuf + (size_t)(j + 1) * NN * 32),
                                            (unsigned*)(Ybuf + (size_t)j * NN * 32),
                                            rowStart, colIdx, dis, j == 0);
  k_gn<4><<<5000, 256, 0, stream>>>(Ybuf, b2, g2, be2, Hbuf);

  // ---- Readout: 2-stage split-K ----
  k_final1<<<1250, 256, 0, stream>>>(Hbuf, Wl, part);
  k_final2<<<8, 256, 0, stream>>>(part, bl, out);
}